// Round 6
// baseline (183.713 us; speedup 1.0000x reference)
//
#include <hip/hip_runtime.h>
#include <hip/hip_bf16.h>

#define CCH 256
#define NPIX 4096
#define NB 8
#define LOG2E 1.4426950408889634f

typedef __attribute__((ext_vector_type(8))) short bf16x8;
typedef __attribute__((ext_vector_type(16))) float f32x16;

typedef __attribute__((address_space(3))) unsigned lds_u32;
typedef const __attribute__((address_space(1))) unsigned glb_u32;
#define GL_LDS16(gp, lp) \
    __builtin_amdgcn_global_load_lds((glb_u32*)(gp), (lds_u32*)(lp), 16, 0, 0)
#define WAITCNT_VM(N) asm volatile("s_waitcnt vmcnt(" #N ")" ::: "memory")

static __device__ __forceinline__ unsigned pkbf(float a, float b) {
    union { __hip_bfloat16 h[2]; unsigned u; } p;
    p.h[0] = __float2bfloat16(a);
    p.h[1] = __float2bfloat16(b);
    return p.u;
}
static __device__ __forceinline__ unsigned short bf1(float a) {
    union { __hip_bfloat16 h; unsigned short s; } p;
    p.h = __float2bfloat16(a);
    return p.s;
}

// ---------------- Kernel 0: pack W fp32 -> bf16, Wb[320][256] ----------------
__global__ void packw_kernel(const float* __restrict__ Wq,
                             const float* __restrict__ Wk,
                             const float* __restrict__ Wv,
                             unsigned short* __restrict__ Wb) {
    int i4 = blockIdx.x * 256 + threadIdx.x;
    if (i4 >= 20480) return;
    int e = i4 * 4;
    const float* src;
    if (e < 8192)       src = Wq + e;
    else if (e < 16384) src = Wk + (e - 8192);
    else                src = Wv + (e - 16384);
    float4 v = *(const float4*)src;
    uint2 o;
    o.x = pkbf(v.x, v.y);
    o.y = pkbf(v.z, v.w);
    *(uint2*)(Wb + e) = o;
}

// ---------------- Kernel 1: QKV via MFMA (unchanged from r5) ----------------
__global__ __launch_bounds__(320) void qkv_kernel(
    const float* __restrict__ x,
    const unsigned short* __restrict__ Wb,
    const float* __restrict__ bq, const float* __restrict__ bk,
    const float* __restrict__ bv,
    unsigned short* __restrict__ q, unsigned short* __restrict__ k,
    unsigned short* __restrict__ v)
{
    __shared__ __align__(16) unsigned xp[128][36];

    const int t   = threadIdx.x;
    const int b   = blockIdx.x >> 7;
    const int px0 = (blockIdx.x & 127) * 32;

    const float4* gx = (const float4*)x + ((size_t)b * CCH * NPIX + px0) / 4;
    for (int i = t; i < 1024; i += 320) {
        int kp = i >> 3, p4 = i & 7;
        float4 lo = gx[(size_t)(2 * kp) * (NPIX / 4) + p4];
        float4 hi = gx[(size_t)(2 * kp + 1) * (NPIX / 4) + p4];
        uint4 pk4;
        pk4.x = pkbf(lo.x, hi.x);
        pk4.y = pkbf(lo.y, hi.y);
        pk4.z = pkbf(lo.z, hi.z);
        pk4.w = pkbf(lo.w, hi.w);
        *(uint4*)&xp[kp][p4 * 4] = pk4;
    }
    __syncthreads();

    const int w  = t >> 6;
    const int lane = t & 63;
    const int qi = lane & 31, h = lane >> 5;

    f32x16 acc[2];
    #pragma unroll
    for (int rt = 0; rt < 2; ++rt)
        #pragma unroll
        for (int r = 0; r < 16; ++r) acc[rt][r] = 0.f;

    #pragma unroll 4
    for (int ks = 0; ks < 16; ++ks) {
        union { unsigned uw[4]; bf16x8 v8; } xb;
        #pragma unroll
        for (int j = 0; j < 4; ++j) xb.uw[j] = xp[ks * 8 + 4 * h + j][qi];
        #pragma unroll
        for (int rt = 0; rt < 2; ++rt) {
            int row = (2 * w + rt) * 32 + qi;
            bf16x8 af = *(const bf16x8*)(Wb + (size_t)row * 256 + ks * 16 + h * 8);
            acc[rt] = __builtin_amdgcn_mfma_f32_32x32x16_bf16(af, xb.v8, acc[rt], 0, 0, 0);
        }
    }

    const int px = px0 + qi;
    const int pxv = px0 + ((qi & 19) | ((qi & 4) << 1) | ((qi & 8) >> 1)); // bits 2<->3
    #pragma unroll
    for (int rt = 0; rt < 2; ++rt) {
        int tile = 2 * w + rt;
        if (tile < 2) {
            const float* bias = (tile == 0) ? bq : bk;
            unsigned short* outp = (tile == 0) ? q : k;
            float scale = (tile == 0) ? LOG2E : 1.0f;
            #pragma unroll
            for (int rg = 0; rg < 4; ++rg) {
                float vv[4];
                #pragma unroll
                for (int j = 0; j < 4; ++j) {
                    int outd = j + 8 * rg + 4 * h;
                    vv[j] = (acc[rt][4 * rg + j] + bias[outd]) * scale;
                }
                uint2 st;
                st.x = pkbf(vv[0], vv[1]);
                st.y = pkbf(vv[2], vv[3]);
                *(uint2*)(outp + ((size_t)b * NPIX + px) * 32 + 8 * rg + 4 * h) = st;
            }
        } else {
            #pragma unroll
            for (int r = 0; r < 16; ++r) {
                int outd = (r & 3) + 8 * (r >> 2) + 4 * h;
                int grow = (tile - 2) * 32 + outd;
                v[((size_t)b * CCH + grow) * NPIX + pxv] = bf1(acc[rt][r] + bv[grow]);
            }
        }
    }
}

// ---------------- Kernel 2: flash attention, counted-vmcnt pipeline ----------
// 32-key subtiles; V triple-buffered, K (64-key macro) double-buffered.
// Prefetch distance = 2 subtiles; main-loop barriers never drain vmcnt to 0.
__global__ __launch_bounds__(256, 2) void attn_kernel(
    const unsigned short* __restrict__ qg,
    const unsigned short* __restrict__ kg,
    const unsigned short* __restrict__ vg,
    const float* __restrict__ x,
    const float* __restrict__ gamma,
    float* __restrict__ out)
{
    __shared__ __align__(16) unsigned short Kl[2][64][4][8];   //  8 KB
    __shared__ __align__(16) unsigned short Vl[3][256][4][8];  // 48 KB

    const int t    = threadIdx.x;
    const int b    = blockIdx.x & 7;          // batch == XCD -> K/V L2-resident
    const int n0   = (blockIdx.x >> 3) * 64;
    const int w    = t >> 6;
    const int lane = t & 63;
    const int qtile = w >> 1, chalf = w & 1;
    const int qi = lane & 31, h = lane >> 5;

    bf16x8 qf[2];
    {
        const unsigned short* qp = qg + ((size_t)b * NPIX + n0 + qtile * 32 + qi) * 32;
        qf[0] = *(const bf16x8*)(qp + h * 8);
        qf[1] = *(const bf16x8*)(qp + 16 + h * 8);
    }

    f32x16 acc[4];
    #pragma unroll
    for (int ct = 0; ct < 4; ++ct)
        #pragma unroll
        for (int r = 0; r < 16; ++r) acc[ct][r] = 0.f;
    float l_run = 0.f;

    // staging identities: slot (row = t>>2, u = t&3), stored chunk = u^(row&3)
    const int srow = t >> 2, su = t & 3, ssw = su ^ (srow & 3);
    const unsigned short* kg_src = kg + ((size_t)b * NPIX + srow) * 32 + ssw * 8;
    const unsigned short* vg_src = vg + ((size_t)b * CCH + srow) * NPIX + ssw * 8;
    char* kl_base = (char*)&Kl[0][0][0][0] + w * 1024;
    char* vl_base = (char*)&Vl[0][0][0][0] + w * 1024;

    auto stageV = [&](int vb, int j) {            // 4 loads/thread
        const unsigned short* s0 = vg_src + 32 * j;
        char* d0 = vl_base + vb * 16384;
        #pragma unroll
        for (int p = 0; p < 4; ++p)
            GL_LDS16(s0 + (size_t)64 * p * NPIX, d0 + p * 4096);
    };
    auto stageK = [&](int kb, int m) {            // 1 load/thread
        GL_LDS16(kg_src + (size_t)2048 * m, kl_base + kb * 4096);
    };

    auto compute = [&](int vbuf, int kbuf, int half) {
        // S^T[key][query] = K · Q^T  (32 keys)
        f32x16 sacc;
        #pragma unroll
        for (int r = 0; r < 16; ++r) sacc[r] = 0.f;
        #pragma unroll
        for (int s = 0; s < 2; ++s) {
            bf16x8 kf = *(const bf16x8*)&Kl[kbuf][half * 32 + qi][(2 * s + h) ^ (qi & 3)][0];
            sacc = __builtin_amdgcn_mfma_f32_32x32x16_bf16(kf, qf[s], sacc, 0, 0, 0);
        }
        // softmax weights (no-max, q prescaled by log2e) -> B-frags in-lane
        bf16x8 pf[2];
        #pragma unroll
        for (int sp = 0; sp < 2; ++sp) {
            union { unsigned uw[4]; bf16x8 v8; } pk;
            float ps = 0.f;
            #pragma unroll
            for (int c = 0; c < 4; ++c) {
                float ea = exp2f(sacc[8 * sp + 2 * c]);
                float eb = exp2f(sacc[8 * sp + 2 * c + 1]);
                ps += ea + eb;
                pk.uw[c] = pkbf(ea, eb);
            }
            l_run += ps;
            pf[sp] = pk.v8;
        }
        // O^T += V^T · P^T
        __builtin_amdgcn_s_setprio(1);
        #pragma unroll
        for (int ct = 0; ct < 4; ++ct) {
            const int c = chalf * 128 + ct * 32 + qi;
            #pragma unroll
            for (int s = 0; s < 2; ++s) {
                bf16x8 vf = *(const bf16x8*)&Vl[vbuf][c][(2 * s + h) ^ (qi & 3)][0];
                acc[ct] = __builtin_amdgcn_mfma_f32_32x32x16_bf16(vf, pf[s], acc[ct], 0, 0, 0);
            }
        }
        __builtin_amdgcn_s_setprio(0);
    };

    // prologue: V(0)+K(0) then V(1); drain first 5, keep V(1) in flight
    stageV(0, 0);
    stageK(0, 0);
    stageV(1, 1);
    WAITCNT_VM(4);
    __builtin_amdgcn_s_barrier();

    int va = 0;                      // V buffer of subtile 2m
    #pragma unroll 1
    for (int m = 0; m < 63; ++m) {
        const int vb1 = (va >= 2) ? va - 2 : va + 1;   // (va+1)%3
        const int vb2 = (va >= 1) ? va - 1 : va + 2;   // (va+2)%3
        const int kb  = m & 1;

        // sub-iter A: subtile 2m
        stageV(vb2, 2 * m + 2);
        stageK(kb ^ 1, m + 1);
        compute(va, kb, 0);
        WAITCNT_VM(5);               // drain V(2m+1); keep V(2m+2)+K(m+1)
        __builtin_amdgcn_s_barrier();

        // sub-iter B: subtile 2m+1
        stageV(va, 2 * m + 3);
        compute(vb1, kb, 1);
        WAITCNT_VM(4);               // drain V(2m+2)+K(m+1); keep V(2m+3)
        __builtin_amdgcn_s_barrier();

        va = vb2;
    }
    // m = 63 peeled (va == 0 here): subtiles 126, 127
    compute(0, 1, 0);
    __syncthreads();                 // drains V(127)
    compute(1, 1, 1);

    // epilogue: out = gamma * O / l + x
    float l = l_run + __shfl_xor(l_run, 32, 64);
    const float rs = gamma[0] / l;
    #pragma unroll
    for (int ct = 0; ct < 4; ++ct) {
        #pragma unroll
        for (int r = 0; r < 16; ++r) {
            int c = chalf * 128 + ct * 32 + (r & 3) + 8 * (r >> 2) + 4 * h;
            size_t off = ((size_t)b * CCH + c) * NPIX + n0 + qtile * 32 + qi;
            out[off] = rs * acc[ct][r] + x[off];
        }
    }
}

extern "C" void kernel_launch(void* const* d_in, const int* in_sizes, int n_in,
                              void* d_out, int out_size, void* d_ws, size_t ws_size,
                              hipStream_t stream) {
    const float* x     = (const float*)d_in[0];
    const float* Wq    = (const float*)d_in[1];
    const float* bq    = (const float*)d_in[2];
    const float* Wk    = (const float*)d_in[3];
    const float* bk    = (const float*)d_in[4];
    const float* Wv    = (const float*)d_in[5];
    const float* bv    = (const float*)d_in[6];
    const float* gamma = (const float*)d_in[7];
    float* out = (float*)d_out;

    unsigned short* Wb = (unsigned short*)d_ws;
    unsigned short* qw = Wb + 320 * 256;
    unsigned short* kw = qw + (size_t)NB * NPIX * 32;
    unsigned short* vw = kw + (size_t)NB * NPIX * 32;

    packw_kernel<<<dim3(80), dim3(256), 0, stream>>>(Wq, Wk, Wv, Wb);
    qkv_kernel<<<dim3(NB * (NPIX / 32)), dim3(320), 0, stream>>>(
        x, Wb, bq, bk, bv, qw, kw, vw);
    attn_kernel<<<dim3(NB * (NPIX / 64)), dim3(256), 0, stream>>>(
        qw, kw, vw, x, gamma, out);
}

// Round 7
// 156.316 us; speedup vs baseline: 1.1753x; 1.1753x over previous
//
#include <hip/hip_runtime.h>
#include <hip/hip_bf16.h>

#define CCH 256
#define NPIX 4096
#define NB 8
#define LOG2E 1.4426950408889634f

typedef __attribute__((ext_vector_type(8))) short bf16x8;
typedef __attribute__((ext_vector_type(16))) float f32x16;

#define SCHED_FENCE() __builtin_amdgcn_sched_barrier(0)
#define BAR_PLAIN() do { SCHED_FENCE(); __builtin_amdgcn_s_barrier(); SCHED_FENCE(); } while (0)
#define BAR_LGKM()  do { SCHED_FENCE(); asm volatile("s_waitcnt lgkmcnt(0)" ::: "memory"); \
                         __builtin_amdgcn_s_barrier(); SCHED_FENCE(); } while (0)

static __device__ __forceinline__ unsigned pkbf(float a, float b) {
    union { __hip_bfloat16 h[2]; unsigned u; } p;
    p.h[0] = __float2bfloat16(a);
    p.h[1] = __float2bfloat16(b);
    return p.u;
}
static __device__ __forceinline__ unsigned short bf1(float a) {
    union { __hip_bfloat16 h; unsigned short s; } p;
    p.h = __float2bfloat16(a);
    return p.s;
}

// ---------------- Kernel 0: pack W fp32 -> bf16, Wb[320][256] ----------------
__global__ void packw_kernel(const float* __restrict__ Wq,
                             const float* __restrict__ Wk,
                             const float* __restrict__ Wv,
                             unsigned short* __restrict__ Wb) {
    int i4 = blockIdx.x * 256 + threadIdx.x;
    if (i4 >= 20480) return;
    int e = i4 * 4;
    const float* src;
    if (e < 8192)       src = Wq + e;
    else if (e < 16384) src = Wk + (e - 8192);
    else                src = Wv + (e - 16384);
    float4 v = *(const float4*)src;
    uint2 o;
    o.x = pkbf(v.x, v.y);
    o.y = pkbf(v.z, v.w);
    *(uint2*)(Wb + e) = o;
}

// ---------------- Kernel 1: QKV via MFMA (unchanged) ----------------
__global__ __launch_bounds__(320) void qkv_kernel(
    const float* __restrict__ x,
    const unsigned short* __restrict__ Wb,
    const float* __restrict__ bq, const float* __restrict__ bk,
    const float* __restrict__ bv,
    unsigned short* __restrict__ q, unsigned short* __restrict__ k,
    unsigned short* __restrict__ v)
{
    __shared__ __align__(16) unsigned xp[128][36];

    const int t   = threadIdx.x;
    const int b   = blockIdx.x >> 7;
    const int px0 = (blockIdx.x & 127) * 32;

    const float4* gx = (const float4*)x + ((size_t)b * CCH * NPIX + px0) / 4;
    for (int i = t; i < 1024; i += 320) {
        int kp = i >> 3, p4 = i & 7;
        float4 lo = gx[(size_t)(2 * kp) * (NPIX / 4) + p4];
        float4 hi = gx[(size_t)(2 * kp + 1) * (NPIX / 4) + p4];
        uint4 pk4;
        pk4.x = pkbf(lo.x, hi.x);
        pk4.y = pkbf(lo.y, hi.y);
        pk4.z = pkbf(lo.z, hi.z);
        pk4.w = pkbf(lo.w, hi.w);
        *(uint4*)&xp[kp][p4 * 4] = pk4;
    }
    __syncthreads();

    const int w  = t >> 6;
    const int lane = t & 63;
    const int qi = lane & 31, h = lane >> 5;

    f32x16 acc[2];
    #pragma unroll
    for (int rt = 0; rt < 2; ++rt)
        #pragma unroll
        for (int r = 0; r < 16; ++r) acc[rt][r] = 0.f;

    #pragma unroll 4
    for (int ks = 0; ks < 16; ++ks) {
        union { unsigned uw[4]; bf16x8 v8; } xb;
        #pragma unroll
        for (int j = 0; j < 4; ++j) xb.uw[j] = xp[ks * 8 + 4 * h + j][qi];
        #pragma unroll
        for (int rt = 0; rt < 2; ++rt) {
            int row = (2 * w + rt) * 32 + qi;
            bf16x8 af = *(const bf16x8*)(Wb + (size_t)row * 256 + ks * 16 + h * 8);
            acc[rt] = __builtin_amdgcn_mfma_f32_32x32x16_bf16(af, xb.v8, acc[rt], 0, 0, 0);
        }
    }

    const int px = px0 + qi;
    const int pxv = px0 + ((qi & 19) | ((qi & 4) << 1) | ((qi & 8) >> 1)); // bits 2<->3
    #pragma unroll
    for (int rt = 0; rt < 2; ++rt) {
        int tile = 2 * w + rt;
        if (tile < 2) {
            const float* bias = (tile == 0) ? bq : bk;
            unsigned short* outp = (tile == 0) ? q : k;
            float scale = (tile == 0) ? LOG2E : 1.0f;
            #pragma unroll
            for (int rg = 0; rg < 4; ++rg) {
                float vv[4];
                #pragma unroll
                for (int j = 0; j < 4; ++j) {
                    int outd = j + 8 * rg + 4 * h;
                    vv[j] = (acc[rt][4 * rg + j] + bias[outd]) * scale;
                }
                uint2 st;
                st.x = pkbf(vv[0], vv[1]);
                st.y = pkbf(vv[2], vv[3]);
                *(uint2*)(outp + ((size_t)b * NPIX + px) * 32 + 8 * rg + 4 * h) = st;
            }
        } else {
            #pragma unroll
            for (int r = 0; r < 16; ++r) {
                int outd = (r & 3) + 8 * (r >> 2) + 4 * h;
                int grow = (tile - 2) * 32 + outd;
                v[((size_t)b * CCH + grow) * NPIX + pxv] = bf1(acc[rt][r] + bv[grow]);
            }
        }
    }
}

// ---------------- Kernel 2: flash attention, split softmax + P-exchange ------
// Wave (qtile, ch): QK+softmax for keys [ch*32, ch*32+32) of each 64-key tile;
// P exchanged lane-aligned via LDS; PV over all 64 keys for channels ch*128..
// All LDS addresses loop-invariant; barriers never drain vmcnt (prefetch rides).
__global__ __launch_bounds__(256) void attn_kernel(
    const unsigned short* __restrict__ qg,
    const unsigned short* __restrict__ kg,
    const unsigned short* __restrict__ vg,
    const float* __restrict__ x,
    const float* __restrict__ gamma,
    float* __restrict__ out)
{
    __shared__ __align__(16) unsigned short Kl[64][4][8];     //  4 KB
    __shared__ __align__(16) unsigned short Vl[256][8][8];    // 32 KB
    __shared__ __align__(16) unsigned short Px[4][2][64][8];  //  8 KB
    __shared__ float Lx[4][64];                               //  1 KB

    const int t    = threadIdx.x;
    const int b    = blockIdx.x & 7;          // batch == XCD -> K/V L2-resident
    const int n0   = (blockIdx.x >> 3) * 64;
    const int w    = t >> 6;
    const int lane = t & 63;
    const int qtile = w >> 1, ch = w & 1;
    const int qi = lane & 31, h = lane >> 5;

    // Q fragments (registers, loop-invariant)
    bf16x8 qf[2];
    {
        const unsigned short* qp = qg + ((size_t)b * NPIX + n0 + qtile * 32 + qi) * 32;
        qf[0] = *(const bf16x8*)(qp + h * 8);
        qf[1] = *(const bf16x8*)(qp + 16 + h * 8);
    }

    f32x16 acc[4];
    #pragma unroll
    for (int ct = 0; ct < 4; ++ct)
        #pragma unroll
        for (int r = 0; r < 16; ++r) acc[ct][r] = 0.f;
    float l_run = 0.f;

    // ---- staging identities (reg-staged; swizzled LDS dest, invariant) ----
    const int srow = t >> 2, su = t & 3;            // K: row, src chunk
    const int vk_g = t >> 3, vk_kc = t & 7;         // V: row group, src chunk
    unsigned short* kl_dst  = &Kl[srow][su ^ (srow & 3)][0];
    unsigned short* vl_dst0 = &Vl[vk_g][vk_kc ^ (vk_g & 7)][0];   // +p*2048 shorts
    const unsigned short* kg_src = kg + ((size_t)b * NPIX + srow) * 32 + su * 8;
    const unsigned short* vg_src = vg + ((size_t)b * CCH + vk_g) * NPIX + vk_kc * 8;

    // ---- compute-side LDS read pointers (all loop-invariant, per-lane) ----
    const unsigned short* krd0 = &Kl[ch * 32 + qi][(0 + h) ^ (qi & 3)][0];
    const unsigned short* krd1 = &Kl[ch * 32 + qi][(2 + h) ^ (qi & 3)][0];
    const unsigned short* vrd_o0 = &Vl[ch * 128 + qi][(4 * ch + 0 + h) ^ (qi & 7)][0];
    const unsigned short* vrd_o1 = &Vl[ch * 128 + qi][(4 * ch + 2 + h) ^ (qi & 7)][0];
    const unsigned short* vrd_p0 = &Vl[ch * 128 + qi][(4 * (ch ^ 1) + 0 + h) ^ (qi & 7)][0];
    const unsigned short* vrd_p1 = &Vl[ch * 128 + qi][(4 * (ch ^ 1) + 2 + h) ^ (qi & 7)][0];
    unsigned short* px_wr0 = &Px[w][0][lane][0];
    unsigned short* px_wr1 = &Px[w][1][lane][0];
    const unsigned short* px_rd0 = &Px[w ^ 1][0][lane][0];
    const unsigned short* px_rd1 = &Px[w ^ 1][1][lane][0];

    // staged registers + prefetch helper
    bf16x8 kreg;
    bf16x8 vreg[8];
    auto LD = [&](int kt1) {
        kreg = *(const bf16x8*)(kg_src + (size_t)kt1 * 2048);
        const unsigned short* vs = vg_src + kt1 * 64;
        #pragma unroll
        for (int p = 0; p < 8; ++p)
            vreg[p] = *(const bf16x8*)(vs + (size_t)p * 32 * NPIX);
    };

    LD(0);

    for (int kt = 0; kt < 64; ++kt) {
        BAR_PLAIN();                       // [A] prev tile's LDS reads consumed
        // stage tile kt (compiler waits vmcnt on reg deps)
        *(bf16x8*)kl_dst = kreg;
        #pragma unroll
        for (int p = 0; p < 8; ++p)
            *(bf16x8*)(vl_dst0 + p * 2048) = vreg[p];
        BAR_LGKM();                        // [B] staging visible (no vmcnt drain)

        if (kt != 63) LD(kt + 1);          // prefetch rides through [C]

        // ---- phase 1: S^T for our 32 keys + softmax weights ----
        f32x16 sacc;
        #pragma unroll
        for (int r = 0; r < 16; ++r) sacc[r] = 0.f;
        sacc = __builtin_amdgcn_mfma_f32_32x32x16_bf16(*(const bf16x8*)krd0, qf[0], sacc, 0, 0, 0);
        sacc = __builtin_amdgcn_mfma_f32_32x32x16_bf16(*(const bf16x8*)krd1, qf[1], sacc, 0, 0, 0);

        bf16x8 pf0, pf1;
        {
            union { unsigned uw[4]; bf16x8 v8; } pk;
            float ps = 0.f;
            #pragma unroll
            for (int c = 0; c < 4; ++c) {
                float ea = exp2f(sacc[2 * c]);
                float eb = exp2f(sacc[2 * c + 1]);
                ps += ea + eb;
                pk.uw[c] = pkbf(ea, eb);
            }
            l_run += ps;
            pf0 = pk.v8;
            *(bf16x8*)px_wr0 = pk.v8;
        }
        {
            union { unsigned uw[4]; bf16x8 v8; } pk;
            float ps = 0.f;
            #pragma unroll
            for (int c = 0; c < 4; ++c) {
                float ea = exp2f(sacc[8 + 2 * c]);
                float eb = exp2f(sacc[8 + 2 * c + 1]);
                ps += ea + eb;
                pk.uw[c] = pkbf(ea, eb);
            }
            l_run += ps;
            pf1 = pk.v8;
            *(bf16x8*)px_wr1 = pk.v8;
        }
        BAR_LGKM();                        // [C] P visible (no vmcnt drain)

        // ---- phase 2: PV over all 64 keys ----
        bf16x8 po0 = *(const bf16x8*)px_rd0;
        bf16x8 po1 = *(const bf16x8*)px_rd1;
        __builtin_amdgcn_s_setprio(1);
        #pragma unroll
        for (int ct = 0; ct < 4; ++ct) {
            bf16x8 vo0 = *(const bf16x8*)(vrd_o0 + ct * 2048);
            bf16x8 vo1 = *(const bf16x8*)(vrd_o1 + ct * 2048);
            bf16x8 vp0 = *(const bf16x8*)(vrd_p0 + ct * 2048);
            bf16x8 vp1 = *(const bf16x8*)(vrd_p1 + ct * 2048);
            acc[ct] = __builtin_amdgcn_mfma_f32_32x32x16_bf16(vo0, pf0, acc[ct], 0, 0, 0);
            acc[ct] = __builtin_amdgcn_mfma_f32_32x32x16_bf16(vo1, pf1, acc[ct], 0, 0, 0);
            acc[ct] = __builtin_amdgcn_mfma_f32_32x32x16_bf16(vp0, po0, acc[ct], 0, 0, 0);
            acc[ct] = __builtin_amdgcn_mfma_f32_32x32x16_bf16(vp1, po1, acc[ct], 0, 0, 0);
        }
        __builtin_amdgcn_s_setprio(0);
    }

    // ---- l exchange + epilogue ----
    Lx[w][lane] = l_run;
    __syncthreads();
    float l = l_run + Lx[w ^ 1][lane];
    l += __shfl_xor(l, 32, 64);
    const float rs = gamma[0] / l;
    #pragma unroll
    for (int ct = 0; ct < 4; ++ct) {
        #pragma unroll
        for (int r = 0; r < 16; ++r) {
            int c = ch * 128 + ct * 32 + (r & 3) + 8 * (r >> 2) + 4 * h;
            size_t off = ((size_t)b * CCH + c) * NPIX + n0 + qtile * 32 + qi;
            out[off] = rs * acc[ct][r] + x[off];
        }
    }
}

extern "C" void kernel_launch(void* const* d_in, const int* in_sizes, int n_in,
                              void* d_out, int out_size, void* d_ws, size_t ws_size,
                              hipStream_t stream) {
    const float* x     = (const float*)d_in[0];
    const float* Wq    = (const float*)d_in[1];
    const float* bq    = (const float*)d_in[2];
    const float* Wk    = (const float*)d_in[3];
    const float* bk    = (const float*)d_in[4];
    const float* Wv    = (const float*)d_in[5];
    const float* bv    = (const float*)d_in[6];
    const float* gamma = (const float*)d_in[7];
    float* out = (float*)d_out;

    unsigned short* Wb = (unsigned short*)d_ws;
    unsigned short* qw = Wb + 320 * 256;
    unsigned short* kw = qw + (size_t)NB * NPIX * 32;
    unsigned short* vw = kw + (size_t)NB * NPIX * 32;

    packw_kernel<<<dim3(80), dim3(256), 0, stream>>>(Wq, Wk, Wv, Wb);
    qkv_kernel<<<dim3(NB * (NPIX / 32)), dim3(320), 0, stream>>>(
        x, Wb, bq, bk, bv, qw, kw, vw);
    attn_kernel<<<dim3(NB * (NPIX / 64)), dim3(256), 0, stream>>>(
        qw, kw, vw, x, gamma, out);
}